// Round 6
// baseline (99.620 us; speedup 1.0000x reference)
//
#include <hip/hip_runtime.h>

#define T_LEN 2048
#define NMODE 8
#define NPP   17   // 8 tau + 9 g (g[0]=g_infy)

// ===========================================================================
// Round 6: recompute-split 2-kernel pipeline.
//
// R5 post-mortem: waitless 2-kernel = ~26us kernel time, but ~46MB of
// intermediate plane round-trips (q, S_infy, caT). Mandatory traffic is only
// 57MB (inputs+outputs). New split:
//   aggK (grid B*15): per tile, compute ONLY the 80-float aggregate
//     (P[8], R[72]) — reads inputs, writes 0.65MB. Warms L3 with inputs.
//   finK (grid B*16): recompute the in-tile scan with zin folded directly
//     from the aggregates (15 predicated batched loads + 15 FMAs — old
//     phaseB, free), write all three output planes ONCE, finally.
// No q/caT/S_infy round-trips; no atomics/flags/memset (kernel boundary
// provides coherence). finK == R4-fused minus the publish/poll protocol.
// Both kernels <= 18.6KB LDS, VGPR<=64 -> 8 blocks/CU.
// ===========================================================================
template <int L, int G>
__global__ __launch_bounds__(256, 8)
void aggK(const float* __restrict__ Se,   // [B,T,3,3]
          const float* __restrict__ tt,   // [B,T]
          const float* __restrict__ pp,   // [B,T,17]
          float* __restrict__ agg,        // [B*TILES][80] P[8] then R[72]
          int B) {
    constexpr int NSTEP = G * L;            // 128
    constexpr int TILES = T_LEN / NSTEP;    // 16
    constexpr int RW    = NSTEP + 1;        // 129
    constexpr int NT    = 256;
    constexpr int AC_K  = L * 16 + 4;       // 260
    // overlay inside AC region (AC dead after scan phase):
    constexpr int OV_R  = 0;                // G*72 = 576
    constexpr int OV_P  = G * 72;           // G*8  = 64
    static_assert(OV_P + G * 8 <= G * AC_K, "overlay fits");
    constexpr int O_INV = G * AC_K;         // 2080
    constexpr int TOTAL = O_INV + RW;       // 2209 floats = 8836 B

    __shared__ __align__(16) float sm[TOTAL];
    float* s_AC  = sm;
    float* s_R   = sm + OV_R;
    float* s_P   = sm + OV_P;
    float* s_inv = sm + O_INV;

    const int tid  = threadIdx.x;
    const int b    = blockIdx.x / (TILES - 1);
    const int tile = blockIdx.x % (TILES - 1);   // 0..14 (tile 15 unused)

    const int base = tile * NSTEP;
    const int off  = (base == 0) ? 0 : 1;
    const int r0   = (base == 0) ? 0 : base - 1;

    const float* ppb = pp + ((size_t)b * T_LEN + r0) * NPP;
    const float* ttb = tt + (size_t)b * T_LEN + r0;

    // ---- per-row 1/sum(g) ----
    for (int i = tid; i < RW; i += NT) {
        const float* gp = ppb + i * NPP + 8;
        float gs = 0.f;
        #pragma unroll
        for (int k = 0; k < 9; ++k) gs += gp[k];
        s_inv[i] = __builtin_amdgcn_rcpf(gs);
    }
    __syncthreads();

    // ---- per-(step,mode) coefficients ----
    for (int i = tid; i < NSTEP * 8; i += NT) {
        int m  = i & 7;
        int ts = i >> 3;
        int rc = ts + off;
        bool first = (base == 0) && (ts == 0);
        int rp = first ? rc : rc - 1;
        float tau_c = ppb[rc * NPP + m];
        float tau_p = ppb[rp * NPP + m];
        float gqh_c = 0.5f * ppb[rc * NPP + 9 + m] * s_inv[rc];
        float gqh_p = 0.5f * ppb[rp * NPP + 9 + m] * s_inv[rp];
        float t_c = ttb[rc];
        float t_p = first ? -ttb[1] : ttb[rp];
        float ee  = __expf((t_p - t_c) * __builtin_amdgcn_rcpf(tau_c + tau_p));
        int kk = ts / L, sl = ts % L;
        s_AC[kk * AC_K + sl * 16 + m]     = ee * ee;              // A
        s_AC[kk * AC_K + sl * 16 + 8 + m] = ee * (gqh_c + gqh_p); // C
    }
    __syncthreads();

    // ---- chunk scans (tid<72, R only) | cumA products (192..255) ----
    float Q[8] = {0,0,0,0,0,0,0,0};
    float cumA_c = 1.f;
    if (tid < 72) {
        const int k = tid / 9;
        const int e = tid - k * 9;
        const float* Sg = Se + (size_t)b * T_LEN * 9 + e;
        const int gbase = base + k * L;

        float dS[L];
        {
            float prev = (base == 0 && k == 0) ? 0.f
                                               : Sg[(size_t)(gbase - 1) * 9];
            #pragma unroll
            for (int s = 0; s < L; ++s) {
                float cur = Sg[(size_t)(gbase + s) * 9];
                dS[s] = cur - prev;
                prev = cur;
            }
        }

        const float4* acp = (const float4*)(s_AC + k * AC_K);
        #pragma unroll
        for (int s = 0; s < L; ++s) {
            float4 a0 = acp[4*s], a1 = acp[4*s+1];
            float4 c0v = acp[4*s+2], c1v = acp[4*s+3];
            float d = dS[s];
            Q[0] = a0.x*Q[0] + c0v.x*d;  Q[1] = a0.y*Q[1] + c0v.y*d;
            Q[2] = a0.z*Q[2] + c0v.z*d;  Q[3] = a0.w*Q[3] + c0v.w*d;
            Q[4] = a1.x*Q[4] + c1v.x*d;  Q[5] = a1.y*Q[5] + c1v.y*d;
            Q[6] = a1.z*Q[6] + c1v.z*d;  Q[7] = a1.w*Q[7] + c1v.w*d;
        }
    } else if (tid >= 192) {
        const int u = tid - 192;
        const int k = u >> 3;
        const int m = u & 7;
        #pragma unroll
        for (int s = 0; s < L; ++s)
            cumA_c *= s_AC[k * AC_K + s * 16 + m];
    }
    __syncthreads();   // last AC reads done -> overlay writable

    if (tid < 72) {
        float4* r4 = (float4*)(s_R + 8 * tid);   // k*72 + e*8 == 8*tid
        r4[0] = make_float4(Q[0], Q[1], Q[2], Q[3]);
        r4[1] = make_float4(Q[4], Q[5], Q[6], Q[7]);
    } else if (tid >= 192) {
        s_P[tid - 192] = cumA_c;
    }
    __syncthreads();

    // ---- compose across chunks; write tile aggregate ----
    if (tid < 72) {
        const int e = tid >> 3;
        const int m = tid & 7;
        float z = 0.f, pprod = 1.f;
        #pragma unroll
        for (int k = 0; k < G; ++k) {
            float Pk = s_P[k * 8 + m];
            z = Pk * z + s_R[k * 72 + tid];
            pprod *= Pk;
        }
        float* ap = agg + ((size_t)b * TILES + tile) * 80;
        ap[8 + tid] = z;
        if (e == 0) ap[m] = pprod;
    }
}

// ===========================================================================
// finK: full per-tile recompute with zin known; writes all three planes.
// ===========================================================================
template <int L, int G>
__global__ __launch_bounds__(256, 8)
void finK(const float* __restrict__ Se,   // [B,T,3,3]
          const float* __restrict__ tt,   // [B,T]
          const float* __restrict__ pp,   // [B,T,17]
          float* __restrict__ out,        // [3,B,T,3,3]
          const float* __restrict__ agg,  // [B*TILES][80]
          int B) {
    constexpr int NSTEP = G * L;            // 128
    constexpr int TILES = T_LEN / NSTEP;    // 16
    constexpr int RW    = NSTEP + 1;        // 129
    constexpr int NT    = 256;
    constexpr int SROW  = NSTEP + 4;        // 132
    constexpr int QT_SZ = 9 * SROW;         // 1188
    constexpr int CA_K  = L * 8 + 4;        // 132
    constexpr int AC_K  = L * 16 + 4;       // 260
    constexpr int O_AC  = QT_SZ + G * CA_K; // 2244
    // overlay inside AC region (AC dead after scan phase):
    constexpr int OV_R  = 0;                     // G*72 = 576
    constexpr int OV_P  = G * 72;                // G*8  = 64
    constexpr int OV_Z  = OV_P + G * 8;          // G*72 = 576
    static_assert(OV_Z + G * 72 <= G * AC_K, "overlay fits");
    constexpr int O_INV = O_AC + G * AC_K;       // 4324
    constexpr int O_GI  = O_INV + RW;            // 4453
    constexpr int O_ZIN = O_GI + RW;             // 4582
    constexpr int TOTAL = O_ZIN + 72;            // 4654 floats = 18616 B
    static_assert(TOTAL * 4 <= 20480, "LDS must allow 8 blocks/CU");
    static_assert(L == 16, "epilogue uses t>>4 / t&15");

    __shared__ __align__(16) float sm[TOTAL];
    float* s_qT  = sm;                       // qsum transposed [e][t]
    float* s_ca  = sm + QT_SZ;               // cumA skewed [k][s][8]
    float* s_AC  = sm + O_AC;                // coeffs (dead after scan)
    float* s_R   = sm + O_AC + OV_R;
    float* s_P   = sm + O_AC + OV_P;
    float* s_Z   = sm + O_AC + OV_Z;
    float* s_inv = sm + O_INV;
    float* s_gi  = sm + O_GI;
    float* s_Zin = sm + O_ZIN;

    const int tid  = threadIdx.x;
    const int b    = blockIdx.x / TILES;
    const int tile = blockIdx.x % TILES;

    const int base = tile * NSTEP;
    const int off  = (base == 0) ? 0 : 1;
    const int r0   = (base == 0) ? 0 : base - 1;

    const float* ppb = pp + ((size_t)b * T_LEN + r0) * NPP;
    const float* ttb = tt + (size_t)b * T_LEN + r0;

    // ---- phase 0: zin fold (tid<72) | inv+gi pass (tid>=72) ----
    if (tid < 72) {
        float zin = 0.f;
        if (tile > 0) {
            const int m = tid & 7;
            const float* ab = agg + (size_t)b * TILES * 80;
            float Pv[TILES - 1], Rv[TILES - 1];
            #pragma unroll
            for (int j = 0; j < TILES - 1; ++j) {
                if (j < tile) {
                    Pv[j] = ab[j * 80 + m];
                    Rv[j] = ab[j * 80 + 8 + tid];
                }
            }
            #pragma unroll
            for (int j = 0; j < TILES - 1; ++j)
                if (j < tile) zin = Pv[j] * zin + Rv[j];
        }
        s_Zin[tid] = zin;
    } else {
        int i = tid - 72;          // 0..183 covers RW=129 in one pass
        if (i < RW) {
            const float* gp = ppb + i * NPP + 8;
            float gs = 0.f;
            #pragma unroll
            for (int k = 0; k < 9; ++k) gs += gp[k];
            float iv = __builtin_amdgcn_rcpf(gs);
            s_inv[i] = iv;
            s_gi[i]  = gp[0] * iv;
        }
    }
    __syncthreads();

    // ---- coefficients ----
    for (int i = tid; i < NSTEP * 8; i += NT) {
        int m  = i & 7;
        int ts = i >> 3;
        int rc = ts + off;
        bool first = (base == 0) && (ts == 0);
        int rp = first ? rc : rc - 1;
        float tau_c = ppb[rc * NPP + m];
        float tau_p = ppb[rp * NPP + m];
        float gqh_c = 0.5f * ppb[rc * NPP + 9 + m] * s_inv[rc];
        float gqh_p = 0.5f * ppb[rp * NPP + 9 + m] * s_inv[rp];
        float t_c = ttb[rc];
        float t_p = first ? -ttb[1] : ttb[rp];
        float ee  = __expf((t_p - t_c) * __builtin_amdgcn_rcpf(tau_c + tau_p));
        int kk = ts / L, sl = ts % L;
        s_AC[kk * AC_K + sl * 16 + m]     = ee * ee;              // A
        s_AC[kk * AC_K + sl * 16 + 8 + m] = ee * (gqh_c + gqh_p); // C
    }
    __syncthreads();

    const size_t nOut = (size_t)B * T_LEN * 9;
    float* o0 = out + ((size_t)b * T_LEN + base) * 9;
    float* o1 = o0 + nOut;
    float* o2 = o0 + 2 * nOut;
    const float4* sv4 = (const float4*)(Se + ((size_t)b * T_LEN + base) * 9);

    // ---- scan: chunk scans (tid<72) | S_infy (72..191) | cumA (192..255) --
    float Q[8] = {0,0,0,0,0,0,0,0};
    float cumA_c = 1.f;
    if (tid < 72) {
        const int k = tid / 9;
        const int e = tid - k * 9;
        const float* Sg = Se + (size_t)b * T_LEN * 9 + e;
        const int gbase = base + k * L;

        float dS[L];
        {
            float prev = (base == 0 && k == 0) ? 0.f
                                               : Sg[(size_t)(gbase - 1) * 9];
            #pragma unroll
            for (int s = 0; s < L; ++s) {
                float cur = Sg[(size_t)(gbase + s) * 9];
                dS[s] = cur - prev;
                prev = cur;
            }
        }

        const float4* acp = (const float4*)(s_AC + k * AC_K);
        #pragma unroll
        for (int s = 0; s < L; ++s) {
            float4 a0 = acp[4*s], a1 = acp[4*s+1];
            float4 c0v = acp[4*s+2], c1v = acp[4*s+3];
            float d = dS[s];
            Q[0] = a0.x*Q[0] + c0v.x*d;  Q[1] = a0.y*Q[1] + c0v.y*d;
            Q[2] = a0.z*Q[2] + c0v.z*d;  Q[3] = a0.w*Q[3] + c0v.w*d;
            Q[4] = a1.x*Q[4] + c1v.x*d;  Q[5] = a1.y*Q[5] + c1v.y*d;
            Q[6] = a1.z*Q[6] + c1v.z*d;  Q[7] = a1.w*Q[7] + c1v.w*d;
            float qs = ((Q[0]+Q[1])+(Q[2]+Q[3])) + ((Q[4]+Q[5])+(Q[6]+Q[7]));
            s_qT[e * SROW + (k * L + s)] = qs;
        }
    } else if (tid < 192) {
        // S_infy plane — hidden behind the chunk scans
        for (int i4 = tid - 72; i4 < NSTEP * 9 / 4; i4 += 120) {
            float4 sv = sv4[i4];
            int i = i4 * 4;
            float f0 = s_gi[(i    ) / 9 + off] * sv.x;
            float f1 = s_gi[(i + 1) / 9 + off] * sv.y;
            float f2 = s_gi[(i + 2) / 9 + off] * sv.z;
            float f3 = s_gi[(i + 3) / 9 + off] * sv.w;
            ((float4*)o1)[i4] = make_float4(f0, f1, f2, f3);
        }
    } else {
        const int u = tid - 192;
        const int k = u >> 3;
        const int m = u & 7;
        #pragma unroll
        for (int s = 0; s < L; ++s) {
            cumA_c *= s_AC[k * AC_K + s * 16 + m];
            s_ca[k * CA_K + s * 8 + m] = cumA_c;
        }
    }
    __syncthreads();   // last AC reads done -> overlay writable

    if (tid < 72) {
        float4* r4 = (float4*)(s_R + 8 * tid);   // k*72 + e*8 == 8*tid
        r4[0] = make_float4(Q[0], Q[1], Q[2], Q[3]);
        r4[1] = make_float4(Q[4], Q[5], Q[6], Q[7]);
    } else if (tid >= 192) {
        s_P[tid - 192] = cumA_c;
    }
    __syncthreads();

    // ---- compose seeded with zin: entering state per chunk ----
    if (tid < 72) {
        const int m = tid & 7;
        float z = s_Zin[tid];
        #pragma unroll
        for (int k = 0; k < G; ++k) {
            s_Z[k * 72 + tid] = z;
            z = s_P[k * 8 + m] * z + s_R[k * 72 + tid];
        }
    }
    __syncthreads();

    // ---- epilogue: final S and Q_sum planes ----
    for (int i4 = tid; i4 < NSTEP * 9 / 4; i4 += NT) {
        float4 sv = sv4[i4];   // L1-warm re-read
        const float svc[4] = {sv.x, sv.y, sv.z, sv.w};
        int i = i4 * 4;
        float q[4], f[4];
        #pragma unroll
        for (int j = 0; j < 4; ++j) {
            int idx = i + j;
            int t = idx / 9, e = idx - t * 9;
            int rc = t + off;
            int k = t >> 4, s = t & 15;
            const float4* ca4 = (const float4*)(s_ca + k * CA_K + s * 8);
            const float4* z4  = (const float4*)(s_Z + k * 72 + e * 8);
            float4 cA = ca4[0], cB = ca4[1];
            float4 zA = z4[0],  zB = z4[1];
            float cr = ((cA.x*zA.x + cA.y*zA.y) + (cA.z*zA.z + cA.w*zA.w))
                     + ((cB.x*zB.x + cB.y*zB.y) + (cB.z*zB.z + cB.w*zB.w));
            q[j] = s_qT[e * SROW + t] + cr;
            f[j] = s_gi[rc] * svc[j];
        }
        ((float4*)o2)[i4] = make_float4(q[0], q[1], q[2], q[3]);
        ((float4*)o0)[i4] = make_float4(f[0]+q[0], f[1]+q[1],
                                        f[2]+q[2], f[3]+q[3]);
    }
}

// ===========================================================================
extern "C" void kernel_launch(void* const* d_in, const int* in_sizes, int n_in,
                              void* d_out, int out_size, void* d_ws, size_t ws_size,
                              hipStream_t stream) {
    const float* Se = (const float*)d_in[0];
    const float* tt = (const float*)d_in[1];
    const float* pp = (const float*)d_in[2];
    float* out = (float*)d_out;

    int B = in_sizes[1] / T_LEN;

    constexpr int L = 16;
    constexpr int G = 8;
    constexpr int NSTEP = G * L;            // 128
    constexpr int TILES = T_LEN / NSTEP;    // 16

    float* agg = (float*)d_ws;              // B*TILES*80 floats

    aggK<L, G><<<B * (TILES - 1), dim3(256), 0, stream>>>(
        Se, tt, pp, agg, B);
    finK<L, G><<<B * TILES, dim3(256), 0, stream>>>(
        Se, tt, pp, out, agg, B);
}